// Round 1
// baseline (425.393 us; speedup 1.0000x reference)
//
#include <hip/hip_runtime.h>

#define NB   8
#define BC   32
#define CCh  32
#define WIN  14
#define WO   6
#define HH   16
#define BKK  288     // 32*3*3
#define CWW  1152    // 32*6*6
#define EPSF 1e-10f
#define HALF_LN_2PI 0.918938533204672741f

__device__ __forceinline__ float red16(float v) {
    v += __shfl_xor(v, 1);
    v += __shfl_xor(v, 2);
    v += __shfl_xor(v, 4);
    v += __shfl_xor(v, 8);
    return v;
}

// Pass A: per (b, n=(c,X,Y)) reduce over m=(B,u,v): sum_R, sum_RV, sum_RV2 -> mu, sigma, a.
// STAGE 0: R = 1/32.  STAGE 1: R recomputed from prev stats; writes next stats set.
// STAGE 2: R recomputed; writes mu and a directly to d_out (same layout).
template<int STAGE>
__global__ __launch_bounds__(256)
void stats_kernel(const float* __restrict__ poses,
                  const float* __restrict__ act,
                  const float* __restrict__ W,
                  const float* __restrict__ beta_v,
                  const float* __restrict__ beta_a,
                  const float* __restrict__ lam,
                  const float* __restrict__ mu_prev,
                  const float* __restrict__ Kp_arr,   // 1/(2*sigma_sq)
                  const float* __restrict__ Cp_arr,   // log_sigma + 0.5*ln(2pi)
                  const float* __restrict__ a_prev,
                  const float* __restrict__ rows_part, // [b][BKK][4]
                  float* __restrict__ mu_out,
                  float* __restrict__ K_out,
                  float* __restrict__ C_out,
                  float* __restrict__ a_out)
{
    __shared__ float poseS[BKK * 16];
    __shared__ float actS[BKK];
    __shared__ float invRowS[BKK];

    const int bid   = blockIdx.x;        // 8 * 36 * 2 = 576
    const int chalf = bid & 1;
    const int xy    = (bid >> 1) % 36;
    const int b     = bid / 72;
    const int X = xy / 6, Y = xy % 6;

    const int tid = threadIdx.x;
    const int h   = tid & 15;
    const int c   = (chalf << 4) + (tid >> 4);
    const int pq  = h >> 2;   // p
    const int r   = h & 3;
    const int n   = c * 36 + xy;

    // stage pose patch: poseS[m][k] = poses[b, B, 2Y+u, 2X+v, k]
    for (int idx = tid; idx < BKK * 16; idx += 256) {
        int m = idx >> 4, k = idx & 15;
        int B = m / 9, uv = m % 9, u = uv / 3, v = uv % 3;
        int row = 2 * Y + u, col = 2 * X + v;
        poseS[idx] = poses[(((b * BC + B) * WIN + row) * WIN + col) * HH + k];
    }
    for (int m = tid; m < BKK; m += 256) {
        int B = m / 9, uv = m % 9, u = uv / 3, v = uv % 3;
        int row = 2 * Y + u, col = 2 * X + v;
        actS[m] = act[((b * BC + B) * WIN + row) * WIN + col];
        if constexpr (STAGE >= 1) {
            const float* rp = rows_part + (b * BKK + m) * 4;
            invRowS[m] = 1.0f / (rp[0] + rp[1] + rp[2] + rp[3] + EPSF);
        }
    }
    __syncthreads();

    float mu_p = 0.f, Kp = 0.f, Cp = 0.f, ap_n = 0.f;
    if constexpr (STAGE >= 1) {
        int base = (b * CWW + n) * HH + h;
        mu_p = mu_prev[base];
        Kp   = Kp_arr[base];
        Cp   = Cp_arr[base];
        ap_n = a_prev[b * CWW + n];
    }

    // W[m][c][p][q] as float4 rows, 16B aligned
    const float4* W4 = reinterpret_cast<const float4*>(W) + c * 4 + pq;

    float sum_R = 0.f, sum_RV = 0.f, sum_RV2 = 0.f;
    for (int m = 0; m < BKK; ++m) {
        float4 w4 = W4[m * 128];
        int pb = m * 16 + r;
        float V = w4.x * poseS[pb]     + w4.y * poseS[pb + 4]
                + w4.z * poseS[pb + 8] + w4.w * poseS[pb + 12];
        float R;
        if constexpr (STAGE == 0) {
            R = 1.0f / 32.0f;
        } else {
            float t    = V - mu_p;
            float pv   = expf(-fmaf(t * t, Kp, Cp));
            float psum = red16(pv);
            R = fmaf(ap_n * psum, invRowS[m], EPSF);
        }
        float Ra = R * actS[m];
        sum_R  += Ra;
        sum_RV  = fmaf(Ra, V, sum_RV);
        sum_RV2 = fmaf(Ra * V, V, sum_RV2);
    }

    float mu     = sum_RV / sum_R;
    float sig    = fmaxf(sum_RV2 / sum_R - mu * mu, 0.0f);
    float logsig = logf(sqrtf(sig) + EPSF);
    float lsum   = red16(logsig);
    float cost   = sum_R * (16.0f * beta_v[c] + lsum);
    float av     = 1.0f / (1.0f + expf(-lam[0] * (beta_a[c] - cost)));

    int base = (b * CWW + n) * HH + h;
    mu_out[base] = mu;
    if constexpr (STAGE < 2) {
        K_out[base] = 1.0f / (2.0f * sig);
        C_out[base] = logsig + HALF_LN_2PI;
    }
    if (h == 0) a_out[b * CWW + n] = av;
}

// Pass B: rows_part[b][m][chunk] = sum over n-chunk of a_prev[b,n] * sum_h p[b,m,n,h]
__global__ __launch_bounds__(256)
void rowsum_kernel(const float* __restrict__ poses,
                   const float* __restrict__ W,
                   const float* __restrict__ mu_prev,
                   const float* __restrict__ Kp_arr,
                   const float* __restrict__ Cp_arr,
                   const float* __restrict__ a_prev,
                   float* __restrict__ rows_part)
{
    const int bid   = blockIdx.x;      // 8 * 18 * 4 = 576
    const int chunk = bid & 3;
    const int mblk  = (bid >> 2) % 18;
    const int b     = bid / 72;
    const int tid = threadIdx.x;
    const int h   = tid & 15;
    const int m   = mblk * 16 + (tid >> 4);
    const int B = m / 9, uv = m % 9, u = uv / 3, v = uv % 3;
    const int pq = h >> 2, r = h & 3;

    const float* poseB = poses + (b * BC + B) * (WIN * WIN * HH);
    const float4* W4 = reinterpret_cast<const float4*>(W) + m * 128 + pq;
    const float* muB = mu_prev + b * CWW * HH + h;
    const float* KB  = Kp_arr  + b * CWW * HH + h;
    const float* CB  = Cp_arr  + b * CWW * HH + h;
    const float* aB  = a_prev  + b * CWW;

    const int c0 = chunk * 8;
    float acc = 0.f;
    for (int X = 0; X < 6; ++X) {
        for (int Y = 0; Y < 6; ++Y) {
            int row = 2 * Y + u, col = 2 * X + v;
            const float* pp = poseB + (row * WIN + col) * HH + r;
            float p0 = pp[0], p1 = pp[4], p2 = pp[8], p3 = pp[12];
            int nxy = X * 6 + Y;
            for (int cc = 0; cc < 8; ++cc) {
                int cidx = c0 + cc;
                int n = cidx * 36 + nxy;
                float4 w4 = W4[cidx * 4];
                float V = w4.x * p0 + w4.y * p1 + w4.z * p2 + w4.w * p3;
                float t  = V - muB[n * HH];
                float pv = expf(-fmaf(t * t, KB[n * HH], CB[n * HH]));
                acc = fmaf(aB[n], pv, acc);
            }
        }
    }
    float tot = red16(acc);
    if (h == 0) rows_part[(b * BKK + m) * 4 + chunk] = tot;
}

extern "C" void kernel_launch(void* const* d_in, const int* in_sizes, int n_in,
                              void* d_out, int out_size, void* d_ws, size_t ws_size,
                              hipStream_t stream) {
    const float* poses  = (const float*)d_in[0];
    const float* act    = (const float*)d_in[1];
    const float* W      = (const float*)d_in[2];
    const float* beta_v = (const float*)d_in[3];
    const float* beta_a = (const float*)d_in[4];
    const float* lam    = (const float*)d_in[5];
    float* out = (float*)d_out;
    float* ws  = (float*)d_ws;

    const int SZ = NB * CWW * HH;  // 147456
    float* mu0 = ws;
    float* K0  = ws + SZ;
    float* C0  = ws + 2 * SZ;
    float* mu1 = ws + 3 * SZ;
    float* K1  = ws + 4 * SZ;
    float* C1  = ws + 5 * SZ;
    float* a0  = ws + 6 * SZ;                 // 9216
    float* a1  = a0 + NB * CWW;               // 9216
    float* rows = a1 + NB * CWW;              // 8*288*4 = 9216

    dim3 blk(256);
    dim3 grdA(NB * 36 * 2);   // 576
    dim3 grdB(NB * 18 * 4);   // 576

    // iter 0 (R = 1/32)
    stats_kernel<0><<<grdA, blk, 0, stream>>>(poses, act, W, beta_v, beta_a, lam,
        nullptr, nullptr, nullptr, nullptr, nullptr, mu0, K0, C0, a0);
    // iter 1
    rowsum_kernel<<<grdB, blk, 0, stream>>>(poses, W, mu0, K0, C0, a0, rows);
    stats_kernel<1><<<grdA, blk, 0, stream>>>(poses, act, W, beta_v, beta_a, lam,
        mu0, K0, C0, a0, rows, mu1, K1, C1, a1);
    // iter 2 (final: write outputs directly; mu then a, identical layouts)
    rowsum_kernel<<<grdB, blk, 0, stream>>>(poses, W, mu1, K1, C1, a1, rows);
    stats_kernel<2><<<grdA, blk, 0, stream>>>(poses, act, W, beta_v, beta_a, lam,
        mu1, K1, C1, a1, rows, out, nullptr, nullptr, out + NB * CWW * HH);
}

// Round 2
// 270.199 us; speedup vs baseline: 1.5744x; 1.5744x over previous
//
#include <hip/hip_runtime.h>
#include <math.h>

#define NB   8
#define BC   32
#define WIN  14
#define HH   16
#define BKK  288     // 32*3*3
#define CWW  1152    // 32*6*6
#define EPSF 1e-10f
#define LOG2E 1.4426950408889634f
#define LN2   0.6931471805599453f
#define L2SQ2PI 1.3257480647361593f  // log2(sqrt(2*pi))

__device__ __forceinline__ float ex2(float x) {
#if __has_builtin(__builtin_amdgcn_exp2f)
    return __builtin_amdgcn_exp2f(x);
#else
    return exp2f(x);
#endif
}
__device__ __forceinline__ float lg2(float x) {
#if __has_builtin(__builtin_amdgcn_logf)
    return __builtin_amdgcn_logf(x);
#else
    return log2f(x);
#endif
}
__device__ __forceinline__ float rcpf(float x) {
#if __has_builtin(__builtin_amdgcn_rcpf)
    return __builtin_amdgcn_rcpf(x);
#else
    return 1.0f / x;
#endif
}

__device__ __forceinline__ float red16(float v) {
    v += __shfl_xor(v, 1);
    v += __shfl_xor(v, 2);
    v += __shfl_xor(v, 4);
    v += __shfl_xor(v, 8);
    return v;
}

// ---------------------------------------------------------------------------
// Pass A (stats): per (b, n=(c,X,Y)) reduce over m: sum_R, sum_RV, sum_RV2.
// 512 threads = 2 m-halves x 16 c x 16 h; LDS combine, then epilogue.
// STAGE 0: R = 1/32. STAGE>=1: R = a_prev[n]*psum[n][m]*invRow[m] + EPS
// (psum precomputed by pv_kernel — no exp / no shuffles in the hot loop).
// STAGE 2 writes mu and a straight into d_out (identical layout).
// ---------------------------------------------------------------------------
template<int STAGE>
__global__ __launch_bounds__(512)
void stats_kernel(const float* __restrict__ poses,
                  const float* __restrict__ act,
                  const float* __restrict__ W,
                  const float* __restrict__ beta_v,
                  const float* __restrict__ beta_a,
                  const float* __restrict__ lam,
                  const float* __restrict__ a_prev,
                  const float* __restrict__ psum,
                  const float* __restrict__ rows_part,   // [b][36][BKK]
                  float* __restrict__ mu_out,
                  float* __restrict__ K2n_out,           // -log2e/(2*sig)
                  float* __restrict__ C2n_out,           // -(log2(sigma)+log2(sqrt(2pi)))
                  float* __restrict__ a_out)
{
    __shared__ float poseS[BKK * 16];
    __shared__ float AIS[BKK];      // act*invRow   (stage0: act/32)
    __shared__ float EAS[BKK];      // EPS*act
    __shared__ float pS[3][256];

    const int bid   = blockIdx.x;        // 8*36*2 = 576
    const int chalf = bid & 1;
    const int xy    = (bid >> 1) % 36;
    const int b     = bid / 72;
    const int X = xy / 6, Y = xy % 6;

    const int tid = threadIdx.x;
    const int h   = tid & 15;
    const int cl  = (tid >> 4) & 15;
    const int mh  = tid >> 8;            // m-half 0/1
    const int c   = (chalf << 4) + cl;
    const int pq  = h >> 2;
    const int r   = h & 3;
    const int n   = c * 36 + xy;

    for (int idx = tid; idx < BKK * 16; idx += 512) {
        int mm = idx >> 4, k = idx & 15;
        int Bq = mm / 9, uv2 = mm % 9, uu = uv2 / 3, vv = uv2 % 3;
        poseS[idx] = poses[(((b * BC + Bq) * WIN + 2 * Y + uu) * WIN + 2 * X + vv) * HH + k];
    }
    for (int mm = tid; mm < BKK; mm += 512) {
        int Bq = mm / 9, uv2 = mm % 9, uu = uv2 / 3, vv = uv2 % 3;
        float am = act[((b * BC + Bq) * WIN + 2 * Y + uu) * WIN + 2 * X + vv];
        if constexpr (STAGE == 0) {
            AIS[mm] = am * (1.0f / 32.0f);
        } else {
            float sr = EPSF;
            const float* rp = rows_part + b * 36 * BKK + mm;
            #pragma unroll
            for (int ch = 0; ch < 36; ++ch) sr += rp[ch * BKK];
            AIS[mm] = am / sr;
            EAS[mm] = EPSF * am;
        }
    }
    __syncthreads();

    float ap_n = 0.0f;
    if constexpr (STAGE >= 1) ap_n = a_prev[b * CWW + n];

    const float4* W4 = reinterpret_cast<const float4*>(W) + (c << 2) + pq;
    const float* psum_n = nullptr;
    if constexpr (STAGE >= 1) psum_n = psum + (b * CWW + n) * BKK;

    float sum_R = 0.0f, sum_RV = 0.0f, sum_RV2 = 0.0f;
    const int m0 = mh * 144, m1 = m0 + 144;
    #pragma unroll 4
    for (int m = m0; m < m1; ++m) {
        float4 w4 = W4[m * 128];
        int pb = (m << 4) + r;
        float V = w4.x * poseS[pb]     + w4.y * poseS[pb + 4]
                + w4.z * poseS[pb + 8] + w4.w * poseS[pb + 12];
        float Ra;
        if constexpr (STAGE == 0) Ra = AIS[m];
        else                      Ra = fmaf(ap_n * psum_n[m], AIS[m], EAS[m]);
        sum_R  += Ra;
        sum_RV  = fmaf(Ra, V, sum_RV);
        sum_RV2 = fmaf(Ra * V, V, sum_RV2);
    }

    if (mh == 1) {
        int i = tid & 255;
        pS[0][i] = sum_R; pS[1][i] = sum_RV; pS[2][i] = sum_RV2;
    }
    __syncthreads();
    if (mh == 0) {
        sum_R  += pS[0][tid];
        sum_RV += pS[1][tid];
        sum_RV2 += pS[2][tid];

        float inv = 1.0f / sum_R;
        float mu  = sum_RV * inv;
        float sig = fmaxf(fmaf(-mu, mu, sum_RV2 * inv), 1e-30f);
        float l2s = lg2(sqrtf(sig) + EPSF);          // log2(sigma+eps)
        float lsum = red16(l2s) * LN2;               // sum_h ln(sigma)
        float cost = sum_R * fmaf(16.0f, beta_v[c], lsum);
        float z  = lam[0] * (beta_a[c] - cost);
        float av = rcpf(1.0f + ex2(-z * LOG2E));

        int base = (b * CWW + n) * HH + h;
        mu_out[base] = mu;
        if constexpr (STAGE < 2) {
            K2n_out[base] = (-0.5f * LOG2E) / sig;
            C2n_out[base] = -(l2s + L2SQ2PI);
        }
        if (h == 0) a_out[b * CWW + n] = av;
    }
}

// ---------------------------------------------------------------------------
// Pass B (pv): thread-per-(m,n). 4x4 register matmul -> 16 p-values ->
// psum[b][n][m] and block-partial row sums rows_part[b][chunk][m].
// Grid: b(8) x mblk(9: 32 m) x nblk(36: 32 n, looped x4). 256 thr = 32m x 8n.
// ---------------------------------------------------------------------------
__global__ __launch_bounds__(256)
void pv_kernel(const float* __restrict__ poses,
               const float* __restrict__ W,
               const float* __restrict__ mu_p,
               const float* __restrict__ K2n,
               const float* __restrict__ C2n,
               const float* __restrict__ a_p,
               float* __restrict__ psum_out,    // [b][n][m]
               float* __restrict__ rows_part)   // [b][36][BKK]
{
    __shared__ float sArr[256];

    const int bid = blockIdx.x;          // 8*9*36 = 2592
    const int nb  = bid % 36;
    const int mb  = (bid / 36) % 9;
    const int b   = bid / 324;
    const int tid = threadIdx.x;
    const int m_i = tid & 31;
    const int n_i = tid >> 5;
    const int m   = mb * 32 + m_i;
    const int B = m / 9, uv = m % 9, u = uv / 3, v = uv % 3;

    const float*  poseB = poses + (b * BC + B) * (WIN * WIN * HH);
    const float4* Wm = reinterpret_cast<const float4*>(W) + m * 128;

    float s = 0.0f;
    #pragma unroll 1
    for (int j = 0; j < 4; ++j) {
        int n = nb * 32 + j * 8 + n_i;
        int c = n / 36, xy = n % 36, X = xy / 6, Y = xy % 6;
        const float4* Pp = reinterpret_cast<const float4*>(
            poseB + ((2 * Y + u) * WIN + (2 * X + v)) * HH);
        float4 P0 = Pp[0], P1 = Pp[1], P2 = Pp[2], P3 = Pp[3];
        const float4* Wp = Wm + (c << 2);
        int nb16 = (b * CWW + n) << 4;
        const float4* Mp = reinterpret_cast<const float4*>(mu_p + nb16);
        const float4* Kp = reinterpret_cast<const float4*>(K2n + nb16);
        const float4* Cp = reinterpret_cast<const float4*>(C2n + nb16);

        float psum = 0.0f;
        #pragma unroll
        for (int p = 0; p < 4; ++p) {
            float4 w = Wp[p], M = Mp[p], Kk = Kp[p], Cc = Cp[p];
            float Vx = w.x * P0.x + w.y * P1.x + w.z * P2.x + w.w * P3.x;
            float Vy = w.x * P0.y + w.y * P1.y + w.z * P2.y + w.w * P3.y;
            float Vz = w.x * P0.z + w.y * P1.z + w.z * P2.z + w.w * P3.z;
            float Vw = w.x * P0.w + w.y * P1.w + w.z * P2.w + w.w * P3.w;
            float tx = Vx - M.x, ty = Vy - M.y, tz = Vz - M.z, tw = Vw - M.w;
            psum += ex2(fmaf(tx * tx, Kk.x, Cc.x));
            psum += ex2(fmaf(ty * ty, Kk.y, Cc.y));
            psum += ex2(fmaf(tz * tz, Kk.z, Cc.z));
            psum += ex2(fmaf(tw * tw, Kk.w, Cc.w));
        }
        psum_out[(b * CWW + n) * BKK + m] = psum;
        s = fmaf(a_p[b * CWW + n], psum, s);
    }

    sArr[tid] = s;
    __syncthreads();
    if (tid < 32) {
        float t = sArr[tid];
        #pragma unroll
        for (int jj = 1; jj < 8; ++jj) t += sArr[jj * 32 + tid];
        rows_part[(b * 36 + nb) * BKK + mb * 32 + tid] = t;
    }
}

extern "C" void kernel_launch(void* const* d_in, const int* in_sizes, int n_in,
                              void* d_out, int out_size, void* d_ws, size_t ws_size,
                              hipStream_t stream) {
    const float* poses  = (const float*)d_in[0];
    const float* act    = (const float*)d_in[1];
    const float* W      = (const float*)d_in[2];
    const float* beta_v = (const float*)d_in[3];
    const float* beta_a = (const float*)d_in[4];
    const float* lam    = (const float*)d_in[5];
    float* out = (float*)d_out;
    float* ws  = (float*)d_ws;

    const int SZ = NB * CWW * HH;            // 147456
    float* mu   = ws;                        // SZ
    float* K2n  = mu + SZ;                   // SZ
    float* C2n  = K2n + SZ;                  // SZ
    float* a    = C2n + SZ;                  // 9216
    float* rows = a + NB * CWW;              // 8*36*288 = 82944
    float* psum = rows + NB * 36 * BKK;      // 8*1152*288 = 2654208

    dim3 blkA(512), grdA(576);
    dim3 blkP(256), grdP(2592);

    // iter 0 (R = 1/32)
    stats_kernel<0><<<grdA, blkA, 0, stream>>>(poses, act, W, beta_v, beta_a, lam,
        nullptr, nullptr, nullptr, mu, K2n, C2n, a);
    // iter 1
    pv_kernel<<<grdP, blkP, 0, stream>>>(poses, W, mu, K2n, C2n, a, psum, rows);
    stats_kernel<1><<<grdA, blkA, 0, stream>>>(poses, act, W, beta_v, beta_a, lam,
        a, psum, rows, mu, K2n, C2n, a);
    // iter 2 (final: mu and a straight to d_out)
    pv_kernel<<<grdP, blkP, 0, stream>>>(poses, W, mu, K2n, C2n, a, psum, rows);
    stats_kernel<2><<<grdA, blkA, 0, stream>>>(poses, act, W, beta_v, beta_a, lam,
        a, psum, rows, out, nullptr, nullptr, out + NB * CWW * HH);
}

// Round 3
// 180.220 us; speedup vs baseline: 2.3604x; 1.4993x over previous
//
#include <hip/hip_runtime.h>
#include <math.h>

#define NB   8
#define BC   32
#define WIN  14
#define HH   16
#define BKK  288     // 32*3*3
#define CWW  1152    // 32*6*6
#define NXY  36
#define EPSF 1e-10f
#define LOG2E 1.4426950408889634f
#define LN2   0.6931471805599453f
#define L2SQ2PI 1.3257480647361593f  // log2(sqrt(2*pi))

__device__ __forceinline__ float ex2(float x) { return __builtin_amdgcn_exp2f(x); }
__device__ __forceinline__ float lg2(float x) { return __builtin_amdgcn_logf(x); }
__device__ __forceinline__ float rcpf(float x) { return __builtin_amdgcn_rcpf(x); }

__device__ __forceinline__ float red16(float v) {
    v += __shfl_xor(v, 1);
    v += __shfl_xor(v, 2);
    v += __shfl_xor(v, 4);
    v += __shfl_xor(v, 8);
    return v;
}

__device__ __forceinline__ float4 f4mul(float s, float4 b) {
    return make_float4(s * b.x, s * b.y, s * b.z, s * b.w);
}
__device__ __forceinline__ float4 f4fma(float s, float4 b, float4 c) {
    return make_float4(fmaf(s, b.x, c.x), fmaf(s, b.y, c.y),
                       fmaf(s, b.z, c.z), fmaf(s, b.w, c.w));
}

// W[m][c][p][q] (float4 rows over q) -> Wt[m][p][c] (float4 over q):
// Wt4[(m*4+p)*32 + c] = W4[(m*32+c)*4 + p]  => c-contiguous loads in compute.
__global__ __launch_bounds__(256)
void wt_kernel(const float4* __restrict__ W4, float4* __restrict__ Wt4) {
    int o = blockIdx.x * 256 + threadIdx.x;   // 288*4*32 = 36864
    if (o < BKK * 128) {
        int c = o & 31, p = (o >> 5) & 3, m = o >> 7;
        Wt4[o] = W4[(m * 32 + c) * 4 + p];
    }
}

// invRowG[b][m] = 1 / (sum_j rows_part[b*72+j][m] + EPS)
__global__ __launch_bounds__(256)
void rowred_kernel(const float* __restrict__ rows_part, float* __restrict__ invRowG) {
    int i = blockIdx.x * 256 + threadIdx.x;   // 8*288 = 2304
    if (i < NB * BKK) {
        int b = i / BKK, m = i % BKK;
        float s = EPSF;
        #pragma unroll 8
        for (int j = 0; j < 72; ++j) s += rows_part[(b * 72 + j) * BKK + m];
        invRowG[i] = 1.0f / s;
    }
}

// ---------------------------------------------------------------------------
// stats: block = (b, xy, chalf); 256 thr = 16 c x 16 mchunk (18 m each).
// Thread computes V[16] per m (float4 x4), accumulates sum_R, sum(Ra*V),
// sum(Ra*V^2) for ALL h; combine over mchunks (shfl + LDS); epilogue per (c,h).
// ---------------------------------------------------------------------------
template<int STAGE, bool FINAL>
__global__ __launch_bounds__(256)
void stats_kernel(const float* __restrict__ poses,
                  const float* __restrict__ act,
                  const float4* __restrict__ Wt4,
                  const float* __restrict__ beta_v,
                  const float* __restrict__ beta_a,
                  const float* __restrict__ lam,
                  const float* __restrict__ aws_in,   // [b][xy][32c]
                  const float* __restrict__ psum,     // [b][m][xy][32c]
                  const float* __restrict__ invRowG,  // [b][288]
                  float* __restrict__ mu_out,         // [b][n][16]
                  float* __restrict__ K2n_out,
                  float* __restrict__ C2n_out,
                  float* __restrict__ a_out)          // ws layout or final layout
{
    __shared__ float4 poseS4[BKK * 4];      // 18432 B
    __shared__ float2 AE[BKK];              // (act*coef, act*EPS)
    __shared__ float4 red4[4 * 16 * 9];     // 9216 B

    const int bid   = blockIdx.x;           // 8*36*2 = 576
    const int chalf = bid & 1;
    const int xy    = (bid >> 1) % NXY;
    const int b     = bid / 72;
    const int X = xy / 6, Y = xy % 6;

    const int tid = threadIdx.x;
    const int c_l = tid & 15;
    const int mch = tid >> 4;               // 0..15
    const int c   = chalf * 16 + c_l;
    const int n   = c * NXY + xy;

    const float4* poses4 = reinterpret_cast<const float4*>(poses);
    for (int idx = tid; idx < BKK * 4; idx += 256) {
        int m = idx >> 2, q = idx & 3;
        int B = m / 9, uv = m % 9, u = uv / 3, v = uv % 3;
        poseS4[idx] = poses4[((b * BC + B) * 196 + (2 * Y + u) * WIN + (2 * X + v)) * 4 + q];
    }
    for (int m = tid; m < BKK; m += 256) {
        int B = m / 9, uv = m % 9, u = uv / 3, v = uv % 3;
        float am = act[(b * BC + B) * 196 + (2 * Y + u) * WIN + (2 * X + v)];
        float ai, ea;
        if constexpr (STAGE == 0) { ai = am * (1.0f / 32.0f); ea = 0.0f; }
        else { ai = am * invRowG[b * BKK + m]; ea = EPSF * am; }
        AE[m] = make_float2(ai, ea);
    }

    float ap_n = 0.0f;
    const float* psum_b = nullptr;
    if constexpr (STAGE >= 1) {
        ap_n   = aws_in[(b * NXY + xy) * 32 + c];
        psum_b = psum + ((b * BKK) * NXY + xy) * 32 + c;   // + m*NXY*32
    }
    __syncthreads();

    const float4* WtB = Wt4 + c;            // + m*128 + p*32

    float  sum_R = 0.0f;
    float4 sRV[4]  = {make_float4(0,0,0,0), make_float4(0,0,0,0), make_float4(0,0,0,0), make_float4(0,0,0,0)};
    float4 sRV2[4] = {make_float4(0,0,0,0), make_float4(0,0,0,0), make_float4(0,0,0,0), make_float4(0,0,0,0)};

    const int m0 = mch * 18;
    #pragma unroll 3
    for (int i = 0; i < 18; ++i) {
        int m = m0 + i;
        float4 w0 = WtB[m * 128 +  0];
        float4 w1 = WtB[m * 128 + 32];
        float4 w2 = WtB[m * 128 + 64];
        float4 w3 = WtB[m * 128 + 96];
        float4 P0 = poseS4[m * 4 + 0];
        float4 P1 = poseS4[m * 4 + 1];
        float4 P2 = poseS4[m * 4 + 2];
        float4 P3 = poseS4[m * 4 + 3];
        float4 V0 = f4fma(w0.w, P3, f4fma(w0.z, P2, f4fma(w0.y, P1, f4mul(w0.x, P0))));
        float4 V1 = f4fma(w1.w, P3, f4fma(w1.z, P2, f4fma(w1.y, P1, f4mul(w1.x, P0))));
        float4 V2 = f4fma(w2.w, P3, f4fma(w2.z, P2, f4fma(w2.y, P1, f4mul(w2.x, P0))));
        float4 V3 = f4fma(w3.w, P3, f4fma(w3.z, P2, f4fma(w3.y, P1, f4mul(w3.x, P0))));
        float Ra;
        if constexpr (STAGE == 0) {
            Ra = AE[m].x;
        } else {
            float ps = psum_b[m * (NXY * 32)];
            float2 ae = AE[m];
            Ra = fmaf(ap_n * ps, ae.x, ae.y);
        }
        sum_R += Ra;
        sRV[0] = f4fma(Ra, V0, sRV[0]);
        sRV[1] = f4fma(Ra, V1, sRV[1]);
        sRV[2] = f4fma(Ra, V2, sRV[2]);
        sRV[3] = f4fma(Ra, V3, sRV[3]);
        float4 q0 = make_float4(V0.x*V0.x, V0.y*V0.y, V0.z*V0.z, V0.w*V0.w);
        float4 q1 = make_float4(V1.x*V1.x, V1.y*V1.y, V1.z*V1.z, V1.w*V1.w);
        float4 q2 = make_float4(V2.x*V2.x, V2.y*V2.y, V2.z*V2.z, V2.w*V2.w);
        float4 q3 = make_float4(V3.x*V3.x, V3.y*V3.y, V3.z*V3.z, V3.w*V3.w);
        sRV2[0] = f4fma(Ra, q0, sRV2[0]);
        sRV2[1] = f4fma(Ra, q1, sRV2[1]);
        sRV2[2] = f4fma(Ra, q2, sRV2[2]);
        sRV2[3] = f4fma(Ra, q3, sRV2[3]);
    }

    // combine the 4 mchunks within each wave (lane bits 4,5)
    {
        float* f1 = reinterpret_cast<float*>(sRV);
        float* f2 = reinterpret_cast<float*>(sRV2);
        #pragma unroll
        for (int k = 0; k < 16; ++k) { f1[k] += __shfl_xor(f1[k], 16); f2[k] += __shfl_xor(f2[k], 16); }
        sum_R += __shfl_xor(sum_R, 16);
        #pragma unroll
        for (int k = 0; k < 16; ++k) { f1[k] += __shfl_xor(f1[k], 32); f2[k] += __shfl_xor(f2[k], 32); }
        sum_R += __shfl_xor(sum_R, 32);
    }
    const int wgrp = tid >> 6;
    if ((tid & 48) == 0) {
        float4* dst = &red4[(wgrp * 16 + c_l) * 9];
        dst[0] = make_float4(sum_R, 0.f, 0.f, 0.f);
        dst[1] = sRV[0];  dst[2] = sRV[1];  dst[3] = sRV[2];  dst[4] = sRV[3];
        dst[5] = sRV2[0]; dst[6] = sRV2[1]; dst[7] = sRV2[2]; dst[8] = sRV2[3];
    }
    __syncthreads();

    // epilogue: thread = (h, cc)
    const int h  = tid & 15;
    const int cc = tid >> 4;
    const float* red = reinterpret_cast<const float*>(red4);
    float sR = 0.f, sV = 0.f, sV2 = 0.f;
    #pragma unroll
    for (int j = 0; j < 4; ++j) {
        int off = (j * 16 + cc) * 36;
        sR  += red[off];
        sV  += red[off + 4 + h];
        sV2 += red[off + 20 + h];
    }
    float inv = 1.0f / sR;
    float mu  = sV * inv;
    float sig = fmaxf(fmaf(-mu, mu, sV2 * inv), 1e-30f);
    float l2s = lg2(sqrtf(sig) + EPSF);          // log2(sigma+eps)
    float lsum = red16(l2s) * LN2;               // sum_h ln(sigma)
    int   cg   = chalf * 16 + cc;
    float cost = sR * fmaf(16.0f, beta_v[cg], lsum);
    float z    = lam[0] * (beta_a[cg] - cost);
    float av   = rcpf(1.0f + ex2(-z * LOG2E));

    int nn   = cg * NXY + xy;
    int base = (b * CWW + nn) * HH + h;
    mu_out[base] = mu;
    if constexpr (!FINAL) {
        K2n_out[base] = (-0.5f * LOG2E) / sig;
        C2n_out[base] = -(l2s + L2SQ2PI);
        if (h == 0) a_out[(b * NXY + xy) * 32 + cg] = av;
    } else {
        if (h == 0) a_out[b * CWW + nn] = av;
    }
}

// ---------------------------------------------------------------------------
// pv: same decomposition; mu/K/C register-resident per thread (fixed n).
// Writes psum[b][m][xy][c] (coalesced) + per-block row partials.
// ---------------------------------------------------------------------------
__global__ __launch_bounds__(256)
void pv_kernel(const float* __restrict__ poses,
               const float4* __restrict__ Wt4,
               const float4* __restrict__ mu4,
               const float4* __restrict__ K4,
               const float4* __restrict__ C4,
               const float* __restrict__ aws,
               float* __restrict__ psum_out,    // [b][m][xy][32c]
               float* __restrict__ rows_part)   // [b*72+chunk][288]
{
    __shared__ float4 poseS4[BKK * 4];

    const int bid   = blockIdx.x;           // 576
    const int chalf = bid & 1;
    const int xy    = (bid >> 1) % NXY;
    const int b     = bid / 72;
    const int X = xy / 6, Y = xy % 6;

    const int tid = threadIdx.x;
    const int c_l = tid & 15;
    const int mch = tid >> 4;
    const int c   = chalf * 16 + c_l;
    const int n   = c * NXY + xy;

    const float4* poses4 = reinterpret_cast<const float4*>(poses);
    for (int idx = tid; idx < BKK * 4; idx += 256) {
        int m = idx >> 2, q = idx & 3;
        int B = m / 9, uv = m % 9, u = uv / 3, v = uv % 3;
        poseS4[idx] = poses4[((b * BC + B) * 196 + (2 * Y + u) * WIN + (2 * X + v)) * 4 + q];
    }

    float4 M[4], Kk[4], Cc[4];
    {
        int nb4 = (b * CWW + n) * 4;
        #pragma unroll
        for (int p = 0; p < 4; ++p) { M[p] = mu4[nb4 + p]; Kk[p] = K4[nb4 + p]; Cc[p] = C4[nb4 + p]; }
    }
    const float ap = aws[(b * NXY + xy) * 32 + c];
    __syncthreads();

    const float4* WtB = Wt4 + c;
    float* ps_out = psum_out + ((b * BKK) * NXY + xy) * 32 + c;
    const int rbase = bid * BKK;

    const int m0 = mch * 18;
    #pragma unroll 3
    for (int i = 0; i < 18; ++i) {
        int m = m0 + i;
        float4 w0 = WtB[m * 128 +  0];
        float4 w1 = WtB[m * 128 + 32];
        float4 w2 = WtB[m * 128 + 64];
        float4 w3 = WtB[m * 128 + 96];
        float4 P0 = poseS4[m * 4 + 0];
        float4 P1 = poseS4[m * 4 + 1];
        float4 P2 = poseS4[m * 4 + 2];
        float4 P3 = poseS4[m * 4 + 3];
        float4 V0 = f4fma(w0.w, P3, f4fma(w0.z, P2, f4fma(w0.y, P1, f4mul(w0.x, P0))));
        float4 V1 = f4fma(w1.w, P3, f4fma(w1.z, P2, f4fma(w1.y, P1, f4mul(w1.x, P0))));
        float4 V2 = f4fma(w2.w, P3, f4fma(w2.z, P2, f4fma(w2.y, P1, f4mul(w2.x, P0))));
        float4 V3 = f4fma(w3.w, P3, f4fma(w3.z, P2, f4fma(w3.y, P1, f4mul(w3.x, P0))));

        float psv = 0.0f;
        {
            float4 t, g;
            t = make_float4(V0.x-M[0].x, V0.y-M[0].y, V0.z-M[0].z, V0.w-M[0].w);
            g = make_float4(fmaf(t.x*t.x, Kk[0].x, Cc[0].x), fmaf(t.y*t.y, Kk[0].y, Cc[0].y),
                            fmaf(t.z*t.z, Kk[0].z, Cc[0].z), fmaf(t.w*t.w, Kk[0].w, Cc[0].w));
            psv += ex2(g.x) + ex2(g.y) + ex2(g.z) + ex2(g.w);
            t = make_float4(V1.x-M[1].x, V1.y-M[1].y, V1.z-M[1].z, V1.w-M[1].w);
            g = make_float4(fmaf(t.x*t.x, Kk[1].x, Cc[1].x), fmaf(t.y*t.y, Kk[1].y, Cc[1].y),
                            fmaf(t.z*t.z, Kk[1].z, Cc[1].z), fmaf(t.w*t.w, Kk[1].w, Cc[1].w));
            psv += ex2(g.x) + ex2(g.y) + ex2(g.z) + ex2(g.w);
            t = make_float4(V2.x-M[2].x, V2.y-M[2].y, V2.z-M[2].z, V2.w-M[2].w);
            g = make_float4(fmaf(t.x*t.x, Kk[2].x, Cc[2].x), fmaf(t.y*t.y, Kk[2].y, Cc[2].y),
                            fmaf(t.z*t.z, Kk[2].z, Cc[2].z), fmaf(t.w*t.w, Kk[2].w, Cc[2].w));
            psv += ex2(g.x) + ex2(g.y) + ex2(g.z) + ex2(g.w);
            t = make_float4(V3.x-M[3].x, V3.y-M[3].y, V3.z-M[3].z, V3.w-M[3].w);
            g = make_float4(fmaf(t.x*t.x, Kk[3].x, Cc[3].x), fmaf(t.y*t.y, Kk[3].y, Cc[3].y),
                            fmaf(t.z*t.z, Kk[3].z, Cc[3].z), fmaf(t.w*t.w, Kk[3].w, Cc[3].w));
            psv += ex2(g.x) + ex2(g.y) + ex2(g.z) + ex2(g.w);
        }
        ps_out[m * (NXY * 32)] = psv;

        float rv = ap * psv;
        rv += __shfl_xor(rv, 1);
        rv += __shfl_xor(rv, 2);
        rv += __shfl_xor(rv, 4);
        rv += __shfl_xor(rv, 8);
        if (c_l == 0) rows_part[rbase + m] = rv;
    }
}

extern "C" void kernel_launch(void* const* d_in, const int* in_sizes, int n_in,
                              void* d_out, int out_size, void* d_ws, size_t ws_size,
                              hipStream_t stream) {
    const float* poses  = (const float*)d_in[0];
    const float* act    = (const float*)d_in[1];
    const float* W      = (const float*)d_in[2];
    const float* beta_v = (const float*)d_in[3];
    const float* beta_a = (const float*)d_in[4];
    const float* lam    = (const float*)d_in[5];
    float* out = (float*)d_out;
    float* ws  = (float*)d_ws;

    const int SZ = NB * CWW * HH;            // 147456
    float* Wt   = ws;                        // 147456
    float* mu   = Wt + SZ;                   // 147456
    float* K2n  = mu + SZ;
    float* C2n  = K2n + SZ;
    float* aws  = C2n + SZ;                  // 9216
    float* rows = aws + NB * CWW;            // 8*72*288 = 165888
    float* invR = rows + NB * 72 * BKK;      // 2304
    float* psum = invR + NB * BKK;           // 8*288*36*32 = 2654208
    // total ~3.36M floats = 13.5 MB

    const float4* Wt4 = (const float4*)Wt;

    wt_kernel<<<dim3(144), dim3(256), 0, stream>>>((const float4*)W, (float4*)Wt);

    // iter 0 (R = 1/32)
    stats_kernel<0, false><<<dim3(576), dim3(256), 0, stream>>>(
        poses, act, Wt4, beta_v, beta_a, lam, nullptr, nullptr, nullptr,
        mu, K2n, C2n, aws);
    // iter 1
    pv_kernel<<<dim3(576), dim3(256), 0, stream>>>(
        poses, Wt4, (const float4*)mu, (const float4*)K2n, (const float4*)C2n,
        aws, psum, rows);
    rowred_kernel<<<dim3(9), dim3(256), 0, stream>>>(rows, invR);
    stats_kernel<1, false><<<dim3(576), dim3(256), 0, stream>>>(
        poses, act, Wt4, beta_v, beta_a, lam, aws, psum, invR,
        mu, K2n, C2n, aws);
    // iter 2 (final: mu and a straight to d_out)
    pv_kernel<<<dim3(576), dim3(256), 0, stream>>>(
        poses, Wt4, (const float4*)mu, (const float4*)K2n, (const float4*)C2n,
        aws, psum, rows);
    rowred_kernel<<<dim3(9), dim3(256), 0, stream>>>(rows, invR);
    stats_kernel<1, true><<<dim3(576), dim3(256), 0, stream>>>(
        poses, act, Wt4, beta_v, beta_a, lam, aws, psum, invR,
        out, nullptr, nullptr, out + SZ);
}